// Round 2
// baseline (389.639 us; speedup 1.0000x reference)
//
#include <hip/hip_runtime.h>
#include <math.h>

// Problem constants (fixed by reference setup_inputs)
#define S      2048
#define DK     64
#define NBH    32            // B*H
#define QROWS  128           // q rows per block (8 waves x 16)
#define NQT    (S / QROWS)   // 16 q-tiles per bh
#define NJ     (S / 16)      // 128 j-steps of 16 K rows each
#define NBLK   (NQT * NBH)   // 512 blocks
#define NTHR   512

typedef __bf16 bf16x8 __attribute__((ext_vector_type(8)));
typedef float  f32x4  __attribute__((ext_vector_type(4)));
typedef float  f32x8  __attribute__((ext_vector_type(8)));

#if __has_builtin(__builtin_amdgcn_exp2f)
#define EXP2F(x) __builtin_amdgcn_exp2f(x)
#else
#define EXP2F(x) exp2f(x)
#endif

__device__ __forceinline__ float gelu_exact(float x) {
    return 0.5f * x * (1.0f + erff(x * 0.70710678118654752f));
}

// ---------------------------------------------------------------------------
// Barrier-free fused attention-stats + MLP head.
// Grid (16 q-tiles, 32 bh), 512 threads = 8 waves, NO LDS in the main loop.
// Rationale: K per bh is 512 KB -> L2-resident (2 MB/XCD working set); LDS
// staging only added barriers + vmcnt drains (last round: MfmaUtil 6.5%,
// VALUBusy 21.6%, occupancy 11.5% -> pure latency exposure). Each wave loads
// its 16(k-rows)x64(d) fp32 B-subtile straight from global (L1/L2-served,
// 2-deep register prefetch), converts to bf16 in-register, and runs
// 2x mfma_f32_16x16x32_bf16 per 16-row step. Waves never sync in the loop;
// a raw s_barrier every 4 steps convoys the 8 waves for L1 line sharing.
// Q is pre-scaled by (1/8)*log2(e) so stats exp is a bare v_exp_f32
// (s' = s*log2e domain; sum/max fixed by *ln2 at the end; p = 2^s' = e^s
// exactly, so Z/Z2/var are unchanged).
// Last block (atomic counter) runs the 3->64->64->1 GELU MLP head.
// ---------------------------------------------------------------------------
__global__ __launch_bounds__(NTHR, 4) void fused_attn_stats_mlp(
    const float* __restrict__ Q, const float* __restrict__ K,
    const float* __restrict__ W1, const float* __restrict__ b1,
    const float* __restrict__ W2, const float* __restrict__ b2,
    const float* __restrict__ W3, const float* __restrict__ b3,
    float* __restrict__ ws, float* __restrict__ out)
{
    __shared__ float headLds[32 * 65 + 96 + 32];   // H1 | feat | logt (head only)
    __shared__ float red[3];
    __shared__ int lastF;

    const int t    = threadIdx.x;
    const int lane = t & 63;
    const int w    = t >> 6;        // wave 0..7 -> q rows [16w,16w+16)
    const int lrow = lane & 15;     // m (A) / n (B) index
    const int lq   = lane >> 4;     // quad: k = lq*8 + j
    const int qt   = blockIdx.x;
    const int bh   = blockIdx.y;

    // ---- A fragments straight from global (once; scaled by log2e/8) ----
    const float* qrow = Q + ((size_t)bh * S + (size_t)qt * QROWS + w * 16 + lrow) * DK;
    const float SC = 0.18033688011112042592f;      // (1/sqrt(64)) * log2(e)
    f32x8 q0 = *(const f32x8*)(qrow + lq * 8);
    f32x8 q1 = *(const f32x8*)(qrow + 32 + lq * 8);
    const bf16x8 a_lo = __builtin_convertvector(q0 * SC, bf16x8);
    const bf16x8 a_hi = __builtin_convertvector(q1 * SC, bf16x8);

    if (t < 3) red[t] = 0.0f;
    __syncthreads();                 // red[] init visible before any wave finishes

    // per-lane B pointer: row (j*16 + lrow), cols [lq*8, lq*8+8) and +32
    const float* kp = K + (size_t)bh * S * DK + (size_t)lrow * DK + lq * 8;

    // per-row state; reg i of C holds q-row (lane>>4)*4 + i, col = lane&15
    float m[4], Zs[4], Z2[4], sm[4];
#pragma unroll
    for (int i = 0; i < 4; ++i) { m[i] = -INFINITY; Zs[i] = 0.f; Z2[i] = 0.f; sm[i] = 0.f; }

    // 2-deep register prefetch of the fp32 fragments
    f32x8 c0a = *(const f32x8*)(kp);
    f32x8 c0b = *(const f32x8*)(kp + 32);
    f32x8 c1a = *(const f32x8*)(kp + 1024);
    f32x8 c1b = *(const f32x8*)(kp + 1024 + 32);

#pragma unroll 4
    for (int j = 0; j < NJ; ++j) {
        const bf16x8 b_lo = __builtin_convertvector(c0a, bf16x8);
        const bf16x8 b_hi = __builtin_convertvector(c0b, bf16x8);
        c0a = c1a; c0b = c1b;
        const int jn = (j + 2 < NJ) ? (j + 2) : j;          // clamp tail
        const float* np = kp + (size_t)jn * (16 * DK);
        c1a = *(const f32x8*)(np);
        c1b = *(const f32x8*)(np + 32);

        f32x4 acc = {0.f, 0.f, 0.f, 0.f};
        acc = __builtin_amdgcn_mfma_f32_16x16x32_bf16(a_lo, b_lo, acc, 0, 0, 0);
        acc = __builtin_amdgcn_mfma_f32_16x16x32_bf16(a_hi, b_hi, acc, 0, 0, 0);
#pragma unroll
        for (int i = 0; i < 4; ++i) {
            const float s = acc[i];          // s' = score * log2e
            const float p = EXP2F(s);        // = e^score exactly
            m[i]  = fmaxf(m[i], s);
            Zs[i] += p;
            Z2[i]  = fmaf(p, p, Z2[i]);
            sm[i] += s;
        }
        // convoy the block's 8 waves for L1 sharing; raw barrier = no vm drain
        if ((j & 3) == 3) __builtin_amdgcn_s_barrier();
    }

    // ---- reduce across the 16 column-lanes sharing each q-row ----
#pragma unroll
    for (int off = 1; off < 16; off <<= 1) {
#pragma unroll
        for (int i = 0; i < 4; ++i) {
            m[i]   = fmaxf(m[i], __shfl_xor(m[i], off, 64));
            Zs[i] += __shfl_xor(Zs[i], off, 64);
            Z2[i] += __shfl_xor(Z2[i], off, 64);
            sm[i] += __shfl_xor(sm[i], off, 64);
        }
    }
    if (lrow == 0) {
        const float LN2 = 0.69314718055994530942f;
        float psum = 0.f, pmax = 0.f, pvar = 0.f;
#pragma unroll
        for (int i = 0; i < 4; ++i) {
            psum += sm[i];
            pmax += m[i];
            const float iz = 1.0f / Zs[i];
            // var(probs, ddof=1) = (sum p^2 * (1/Z)^2 - 1/n)/(n-1); scale-inv
            pvar += (Z2[i] * iz * iz - (1.0f / 2048.0f)) * (1.0f / 2047.0f);
        }
        atomicAdd(&red[0], psum * LN2);     // back to natural-log domain
        atomicAdd(&red[1], pmax * LN2);
        atomicAdd(&red[2], pvar);
    }
    __syncthreads();
    if (t == 0) {
        atomicAdd(&ws[bh * 3 + 0], red[0]);
        atomicAdd(&ws[bh * 3 + 1], red[1]);
        atomicAdd(&ws[bh * 3 + 2], red[2]);
        __threadfence();
        const int old = atomicAdd((int*)(ws + 96), 1);
        lastF = (old == NBLK - 1);
    }
    __syncthreads();
    if (!lastF) return;

    // =========================== MLP head (last block) ======================
    float* H1    = headLds;             // 32*65 floats
    float* featL = headLds + 32 * 65;   // 96 floats
    float* logtL = featL + 96;          // 32 floats

    if (t < 96)               featL[t] = atomicAdd(&ws[t], 0.0f); // coherent read
    if (t >= 96 && t < 128)   logtL[t - 96] = 0.0f;
    __syncthreads();

    if (t < 64) {
        const float w1a = W1[t], w1b = W1[64 + t], w1c = W1[128 + t], bb1 = b1[t];
        for (int b = 0; b < 32; ++b) {
            const float f0 = featL[b * 3 + 0] * (1.0f / ((float)S * (float)S));
            const float f1 = featL[b * 3 + 1] * (1.0f / (float)S);
            const float f2 = featL[b * 3 + 2] * (1.0f / (float)S);
            H1[b * 65 + t] = gelu_exact(f0 * w1a + f1 * w1b + f2 * w1c + bb1);
        }
    }
    __syncthreads();
    {
        // 512 threads: 16 threads per bh, 4 hidden-2 units each
        const int b = t >> 4, jb = (t & 15) * 4;
        float a0 = 0.f, a1 = 0.f, a2 = 0.f, a3 = 0.f;
        for (int k = 0; k < 64; ++k) {
            const float hk = H1[b * 65 + k];
            const float4 wa = *(const float4*)&W2[k * 64 + jb];
            a0 += hk * wa.x; a1 += hk * wa.y; a2 += hk * wa.z; a3 += hk * wa.w;
        }
        const float part = gelu_exact(a0 + b2[jb + 0]) * W3[jb + 0]
                         + gelu_exact(a1 + b2[jb + 1]) * W3[jb + 1]
                         + gelu_exact(a2 + b2[jb + 2]) * W3[jb + 2]
                         + gelu_exact(a3 + b2[jb + 3]) * W3[jb + 3];
        atomicAdd(&logtL[b], part);
    }
    __syncthreads();
    if (t < 32) {
        float lt = logtL[t] + b3[0];
        lt = fminf(fmaxf(lt, -2.3025850929940457f), 2.3025850929940457f);
        out[t] = expf(lt);
    }
}

// ---------------------------------------------------------------------------
extern "C" void kernel_launch(void* const* d_in, const int* in_sizes, int n_in,
                              void* d_out, int out_size, void* d_ws, size_t ws_size,
                              hipStream_t stream)
{
    const float* Q  = (const float*)d_in[0];
    const float* K  = (const float*)d_in[1];
    const float* W1 = (const float*)d_in[2];
    const float* b1 = (const float*)d_in[3];
    const float* W2 = (const float*)d_in[4];
    const float* b2 = (const float*)d_in[5];
    const float* W3 = (const float*)d_in[6];
    const float* b3 = (const float*)d_in[7];
    float* out = (float*)d_out;
    float* ws  = (float*)d_ws;

    // zero the 96 stat accumulators + the int block counter at ws[96]
    hipMemsetAsync(ws, 0, 512, stream);

    dim3 grid(NQT, NBH);
    fused_attn_stats_mlp<<<grid, NTHR, 0, stream>>>(Q, K, W1, b1, W2, b2, W3, b3, ws, out);
}

// Round 3
// 186.883 us; speedup vs baseline: 2.0849x; 2.0849x over previous
//
#include <hip/hip_runtime.h>
#include <math.h>

// Problem constants (fixed by reference setup_inputs)
#define S      2048
#define DK     64
#define NBH    32            // B*H
#define QROWS  64            // q rows per block (4 waves x 16)
#define NQT    (S / QROWS)   // 32 q-tiles per bh
#define NKT    (S / 64)      // 32 k-chunks of 64 rows
#define NBLK   (NQT * NBH)   // 1024 blocks
#define NTHR   256

typedef __bf16 bf16x4 __attribute__((ext_vector_type(4)));
typedef __bf16 bf16x8 __attribute__((ext_vector_type(8)));
typedef float  f32x4  __attribute__((ext_vector_type(4)));
typedef float  f32x8  __attribute__((ext_vector_type(8)));

#if __has_builtin(__builtin_amdgcn_exp2f)
#define EXP2F(x) __builtin_amdgcn_exp2f(x)
#else
#define EXP2F(x) exp2f(x)
#endif

__device__ __forceinline__ float gelu_exact(float x) {
    return 0.5f * x * (1.0f + erff(x * 0.70710678118654752f));
}

// ---------------------------------------------------------------------------
// Fused attention-stats + MLP head.  Grid (32 bh, 32 q-tiles) -- bh on
// blockIdx.x so round-robin XCD dispatch pins each bh's K stream to one
// XCD's L2 (4 bh x 512 KB = 2 MB per XCD).  256 threads = 4 waves; 1024
// blocks -> 4 independent barrier domains per CU (fine-grained stall
// overlap).  Main loop: 2-chunk-deep register prefetch (two named reg sets,
// statically indexed via a 2-unrolled chunk loop), double-buffered LDS K,
// ONE raw s_barrier + lgkmcnt(0) per chunk; vmcnt is never drained -- loads
// stay in flight across 2 compute phases + 2 barriers (~600+ cyc slack).
// Each wave: 16(q) x 64(k) strip per chunk via 8x mfma_f32_16x16x32_bf16,
// then per-row no-max softmax stats (m, Z=sum 2^s', Z2=sum 2^2s', sm=sum s')
// in the log2 domain: Q pre-scaled by (1/8)*log2(e) so exp is one
// v_exp_f32; sum/max fixed by *ln2 at the end, Z/Z2/var unchanged.
// Last block (atomic counter) runs the 3->64->64->1 GELU MLP head.
// ---------------------------------------------------------------------------
__global__ __launch_bounds__(NTHR) void fused_attn_stats_mlp(
    const float* __restrict__ Q, const float* __restrict__ K,
    const float* __restrict__ W1, const float* __restrict__ b1,
    const float* __restrict__ W2, const float* __restrict__ b2,
    const float* __restrict__ W3, const float* __restrict__ b3,
    float* __restrict__ ws, float* __restrict__ out)
{
    __shared__ __align__(16) __bf16 Ks[2][64][72];   // double-buffered K chunk
    __shared__ float red[3];
    __shared__ int lastF;

    const int t    = threadIdx.x;
    const int lane = t & 63;
    const int w    = t >> 6;        // wave 0..3 -> q rows [16w,16w+16)
    const int lrow = lane & 15;     // m (A) / n (B) index
    const int lq   = lane >> 4;     // quad: k = lq*8 + j
    const int bh   = blockIdx.x;
    const int qt   = blockIdx.y;

    const float* Kb = Kb = K + (size_t)bh * S * DK;

    // ---- per-chunk staging: thread t owns float4s {t, 256+t, 512+t, 768+t}
    // of the 64x64 chunk (1024 float4s). Coalesced: one dwordx4/instr/lane.
#define ISSUE(r0, r1, r2, r3, c) {                                   \
        const float* _b = Kb + (size_t)(c) * 4096 + t * 4;           \
        r0 = *(const f32x4*)(_b);                                    \
        r1 = *(const f32x4*)(_b + 1024);                             \
        r2 = *(const f32x4*)(_b + 2048);                             \
        r3 = *(const f32x4*)(_b + 3072); }

#define STQ(buf, lin, v) {                                           \
        bf16x4 _o = __builtin_convertvector((v), bf16x4);            \
        *(bf16x4*)&buf[(lin) >> 4][((lin) & 15) * 4] = _o; }

#define WRITE(buf, r0, r1, r2, r3) {                                 \
        STQ(buf, t,       r0); STQ(buf, 256 + t, r1);                \
        STQ(buf, 512 + t, r2); STQ(buf, 768 + t, r3); }

#define PIPE_BAR() {                                                 \
        asm volatile("s_waitcnt lgkmcnt(0)" ::: "memory");           \
        __builtin_amdgcn_s_barrier();                                \
        asm volatile("" ::: "memory"); }

#define COMPUTE(buf) {                                               \
        _Pragma("unroll")                                            \
        for (int ct = 0; ct < 4; ++ct) {                             \
            const bf16x8 b_lo = *(const bf16x8*)&buf[ct * 16 + lrow][lq * 8];      \
            const bf16x8 b_hi = *(const bf16x8*)&buf[ct * 16 + lrow][32 + lq * 8]; \
            f32x4 acc = {0.f, 0.f, 0.f, 0.f};                        \
            acc = __builtin_amdgcn_mfma_f32_16x16x32_bf16(a_lo, b_lo, acc, 0, 0, 0); \
            acc = __builtin_amdgcn_mfma_f32_16x16x32_bf16(a_hi, b_hi, acc, 0, 0, 0); \
            _Pragma("unroll")                                        \
            for (int i = 0; i < 4; ++i) {                            \
                const float s = acc[i];                              \
                const float p = EXP2F(s);                            \
                m[i]  = fmaxf(m[i], s);                              \
                Zs[i] += p;                                          \
                Z2[i]  = fmaf(p, p, Z2[i]);                          \
                sm[i] += s;                                          \
            }                                                        \
        } }

    // ---- prologue: chunks 0,1 in flight; A-fragments from global ----
    f32x4 ra0, ra1, ra2, ra3, rb0, rb1, rb2, rb3;
    ISSUE(ra0, ra1, ra2, ra3, 0);
    ISSUE(rb0, rb1, rb2, rb3, 1);

    const float* qrow = Q + ((size_t)bh * S + (size_t)qt * QROWS + w * 16 + lrow) * DK;
    const float SC = 0.18033688011112042592f;      // (1/sqrt(64)) * log2(e)
    f32x8 q0 = *(const f32x8*)(qrow + lq * 8);
    f32x8 q1 = *(const f32x8*)(qrow + 32 + lq * 8);
    const bf16x8 a_lo = __builtin_convertvector(q0 * SC, bf16x8);
    const bf16x8 a_hi = __builtin_convertvector(q1 * SC, bf16x8);

    if (t < 3) red[t] = 0.0f;

    WRITE(Ks[0], ra0, ra1, ra2, ra3);   // implicit vmcnt wait on chunk 0 only
    ISSUE(ra0, ra1, ra2, ra3, 2);
    PIPE_BAR();

    float m[4], Zs[4], Z2[4], sm[4];
#pragma unroll
    for (int i = 0; i < 4; ++i) { m[i] = -INFINITY; Zs[i] = 0.f; Z2[i] = 0.f; sm[i] = 0.f; }

    // ---- main loop: 2 chunks per iteration (static ra/rb slot parity) ----
    for (int kt = 0; kt < NKT; kt += 2) {
        COMPUTE(Ks[0]);                                   // chunk kt
        {   // stage chunk kt+1 (rb), refill rb with chunk kt+3
            WRITE(Ks[1], rb0, rb1, rb2, rb3);
            const int c = (kt + 3 < NKT) ? kt + 3 : NKT - 1;
            ISSUE(rb0, rb1, rb2, rb3, c);
            PIPE_BAR();
        }
        COMPUTE(Ks[1]);                                   // chunk kt+1
        if (kt + 2 < NKT) {                               // stage chunk kt+2 (ra)
            WRITE(Ks[0], ra0, ra1, ra2, ra3);
            const int c = (kt + 4 < NKT) ? kt + 4 : NKT - 1;
            ISSUE(ra0, ra1, ra2, ra3, c);
            PIPE_BAR();
        }
    }

    // ---- reduce across the 16 column-lanes sharing each q-row ----
#pragma unroll
    for (int off = 1; off < 16; off <<= 1) {
#pragma unroll
        for (int i = 0; i < 4; ++i) {
            m[i]   = fmaxf(m[i], __shfl_xor(m[i], off, 64));
            Zs[i] += __shfl_xor(Zs[i], off, 64);
            Z2[i] += __shfl_xor(Z2[i], off, 64);
            sm[i] += __shfl_xor(sm[i], off, 64);
        }
    }
    if (lrow == 0) {
        const float LN2 = 0.69314718055994530942f;
        float psum = 0.f, pmax = 0.f, pvar = 0.f;
#pragma unroll
        for (int i = 0; i < 4; ++i) {
            psum += sm[i];
            pmax += m[i];
            const float iz = 1.0f / Zs[i];
            // var(probs, ddof=1) = (sum p^2 * (1/Z)^2 - 1/n)/(n-1); scale-inv
            pvar += (Z2[i] * iz * iz - (1.0f / 2048.0f)) * (1.0f / 2047.0f);
        }
        atomicAdd(&red[0], psum * LN2);     // back to natural-log domain
        atomicAdd(&red[1], pmax * LN2);
        atomicAdd(&red[2], pvar);
    }
    __syncthreads();
    if (t == 0) {
        atomicAdd(&ws[bh * 3 + 0], red[0]);
        atomicAdd(&ws[bh * 3 + 1], red[1]);
        atomicAdd(&ws[bh * 3 + 2], red[2]);
        __threadfence();
        const int old = atomicAdd((int*)(ws + 96), 1);
        lastF = (old == NBLK - 1);
    }
    __syncthreads();
    if (!lastF) return;

    // =========================== MLP head (last block) ======================
    float* H1    = (float*)&Ks[0][0][0];   // 32*65 floats
    float* featL = H1 + 32 * 65;           // 96 floats
    float* logtL = featL + 96;             // 32 floats  (total 8832 B < 18 KB)

    if (t < 96)               featL[t] = atomicAdd(&ws[t], 0.0f); // coherent read
    if (t >= 96 && t < 128)   logtL[t - 96] = 0.0f;
    __syncthreads();

    if (t < 64) {
        const float w1a = W1[t], w1b = W1[64 + t], w1c = W1[128 + t], bb1 = b1[t];
        for (int b = 0; b < 32; ++b) {
            const float f0 = featL[b * 3 + 0] * (1.0f / ((float)S * (float)S));
            const float f1 = featL[b * 3 + 1] * (1.0f / (float)S);
            const float f2 = featL[b * 3 + 2] * (1.0f / (float)S);
            H1[b * 65 + t] = gelu_exact(f0 * w1a + f1 * w1b + f2 * w1c + bb1);
        }
    }
    __syncthreads();
    {
        // 256 threads: 8 threads per bh, 8 hidden-2 units each
        const int b = t >> 3, jb = (t & 7) * 8;
        float acc[8];
#pragma unroll
        for (int u = 0; u < 8; ++u) acc[u] = 0.0f;
        for (int k = 0; k < 64; ++k) {
            const float hk = H1[b * 65 + k];
            const float4 wa = *(const float4*)&W2[k * 64 + jb];
            const float4 wb = *(const float4*)&W2[k * 64 + jb + 4];
            acc[0] += hk * wa.x; acc[1] += hk * wa.y;
            acc[2] += hk * wa.z; acc[3] += hk * wa.w;
            acc[4] += hk * wb.x; acc[5] += hk * wb.y;
            acc[6] += hk * wb.z; acc[7] += hk * wb.w;
        }
        float part = 0.0f;
#pragma unroll
        for (int u = 0; u < 8; ++u)
            part += gelu_exact(acc[u] + b2[jb + u]) * W3[jb + u];
        atomicAdd(&logtL[b], part);
    }
    __syncthreads();
    if (t < 32) {
        float lt = logtL[t] + b3[0];
        lt = fminf(fmaxf(lt, -2.3025850929940457f), 2.3025850929940457f);
        out[t] = expf(lt);
    }
}

// ---------------------------------------------------------------------------
extern "C" void kernel_launch(void* const* d_in, const int* in_sizes, int n_in,
                              void* d_out, int out_size, void* d_ws, size_t ws_size,
                              hipStream_t stream)
{
    const float* Q  = (const float*)d_in[0];
    const float* K  = (const float*)d_in[1];
    const float* W1 = (const float*)d_in[2];
    const float* b1 = (const float*)d_in[3];
    const float* W2 = (const float*)d_in[4];
    const float* b2 = (const float*)d_in[5];
    const float* W3 = (const float*)d_in[6];
    const float* b3 = (const float*)d_in[7];
    float* out = (float*)d_out;
    float* ws  = (float*)d_ws;

    // zero the 96 stat accumulators + the int block counter at ws[96]
    hipMemsetAsync(ws, 0, 512, stream);

    dim3 grid(NBH, NQT);   // bh fastest -> each bh's K pinned to one XCD L2
    fused_attn_stats_mlp<<<grid, NTHR, 0, stream>>>(Q, K, W1, b1, W2, b2, W3, b3, ws, out);
}

// Round 4
// 177.647 us; speedup vs baseline: 2.1933x; 1.0520x over previous
//
#include <hip/hip_runtime.h>
#include <math.h>

// Problem constants (fixed by reference setup_inputs)
#define S      2048
#define DK     64
#define NBH    32            // B*H
#define QROWS  64            // q rows per block (4 waves x 16)
#define NQT    (S / QROWS)   // 32 q-tiles per bh
#define NKT    (S / 64)      // 32 k-chunks of 64 rows
#define NBLK   (NQT * NBH)   // 1024 blocks
#define NTHR   256

typedef __bf16 bf16x8 __attribute__((ext_vector_type(8)));
typedef float  f32x4  __attribute__((ext_vector_type(4)));
typedef float  f32x8  __attribute__((ext_vector_type(8)));

#if __has_builtin(__builtin_amdgcn_exp2f)
#define EXP2F(x) __builtin_amdgcn_exp2f(x)
#else
#define EXP2F(x) exp2f(x)
#endif

__device__ __forceinline__ float gelu_exact(float x) {
    return 0.5f * x * (1.0f + erff(x * 0.70710678118654752f));
}

// ---------------------------------------------------------------------------
// Fused attention-stats + MLP head.  Grid (32 bh, 32 qt), 256 thr = 4 waves.
// bh on blockIdx.x -> XCD-pinned K streams (r3: FETCH 74->16.5 MB, keep).
// K is staged as bf16 in TRIPLE-buffered LDS (3 x 64 x 72 rows) with ONE raw
// s_barrier per chunk:  WRITE(regs c+1 -> buf[(c+1)%3]); ISSUE(c+2 -> regs);
// lgkmcnt(0); s_barrier; COMPUTE(buf[c%3]).  Triple buffering makes the
// single barrier race-free (writer of a buffer and its last reader are
// always separated by a barrier).  Global loads are NEVER vmcnt-drained at
// the barrier; the consume wait lands one full iteration after issue (T14).
// Staging: thread t owns one 32-B bf16 segment (row t>>2, cols (t&3)*16),
// conflict-free ds_write_b128 pairs; [72] row padding makes fragment
// ds_read_b128 bank-balanced.  Each wave computes a 16(q)x64(k) strip per
// chunk via 8x mfma_f32_16x16x32_bf16, then per-row no-max softmax stats
// (m, Z=sum 2^s', Z2=sum 2^2s', sm=sum s') in the log2 domain (Q pre-scaled
// by (1/8)*log2 e; sum/max restored by *ln2 at the end; Z/Z2/var invariant).
// Last block (atomic counter) runs the 3->64->64->1 GELU MLP head.
// ---------------------------------------------------------------------------
__global__ __launch_bounds__(NTHR) void fused_attn_stats_mlp(
    const float* __restrict__ Q, const float* __restrict__ K,
    const float* __restrict__ W1, const float* __restrict__ b1,
    const float* __restrict__ W2, const float* __restrict__ b2,
    const float* __restrict__ W3, const float* __restrict__ b3,
    float* __restrict__ ws, float* __restrict__ out)
{
    __shared__ __align__(16) __bf16 Ks[3][64][72];   // 27.6 KB triple buffer
    __shared__ float red[3];
    __shared__ int lastF;

    const int t    = threadIdx.x;
    const int lane = t & 63;
    const int w    = t >> 6;        // wave 0..3 -> q rows [16w,16w+16)
    const int lrow = lane & 15;     // A-row / B-row index within fragment
    const int lq   = lane >> 4;     // quad: k = lq*8 + j
    const int bh   = blockIdx.x;
    const int qt   = blockIdx.y;

    // staging: thread t owns row t>>2, cols [(t&3)*16, +16) of each chunk
    const float* gK = K + (size_t)bh * S * DK + (size_t)(t >> 2) * DK + (t & 3) * 16;

    f32x4 r0, r1, r2, r3;                       // one in-flight chunk segment
#define ISSUE(c) {                                                    \
        const int _cc = (c) < NKT ? (c) : NKT - 1;                    \
        const float* _p = gK + (size_t)_cc * 4096;                    \
        r0 = *(const f32x4*)(_p);      r1 = *(const f32x4*)(_p + 4);  \
        r2 = *(const f32x4*)(_p + 8);  r3 = *(const f32x4*)(_p + 12); }

#define WRITE(dst) {                                                  \
        f32x8 _lo = __builtin_shufflevector(r0, r1, 0,1,2,3,4,5,6,7); \
        f32x8 _hi = __builtin_shufflevector(r2, r3, 0,1,2,3,4,5,6,7); \
        *(bf16x8*)&dst[t >> 2][(t & 3) * 16]     = __builtin_convertvector(_lo, bf16x8); \
        *(bf16x8*)&dst[t >> 2][(t & 3) * 16 + 8] = __builtin_convertvector(_hi, bf16x8); }

#define COMPUTE(src) {                                                \
        _Pragma("unroll")                                             \
        for (int ct = 0; ct < 4; ++ct) {                              \
            const bf16x8 _blo = *(const bf16x8*)&src[ct * 16 + lrow][lq * 8];      \
            const bf16x8 _bhi = *(const bf16x8*)&src[ct * 16 + lrow][32 + lq * 8]; \
            f32x4 _acc = {0.f, 0.f, 0.f, 0.f};                        \
            _acc = __builtin_amdgcn_mfma_f32_16x16x32_bf16(a_lo, _blo, _acc, 0, 0, 0); \
            _acc = __builtin_amdgcn_mfma_f32_16x16x32_bf16(a_hi, _bhi, _acc, 0, 0, 0); \
            _Pragma("unroll")                                         \
            for (int i = 0; i < 4; ++i) {                             \
                const float s = _acc[i];                              \
                const float p = EXP2F(s);                             \
                m[i]  = fmaxf(m[i], s);                               \
                Zs[i] += p;                                           \
                Z2[i]  = fmaf(p, p, Z2[i]);                           \
                sm[i] += s;                                           \
            }                                                         \
        } }

    // ---- prologue ----
    ISSUE(0);                                   // chunk 0 -> regs

    const float* qrow = Q + ((size_t)bh * S + (size_t)qt * QROWS + w * 16 + lrow) * DK;
    const float SC = 0.18033688011112042592f;   // (1/sqrt(64)) * log2(e)
    f32x8 q0 = *(const f32x8*)(qrow + lq * 8);
    f32x8 q1 = *(const f32x8*)(qrow + 32 + lq * 8);
    const bf16x8 a_lo = __builtin_convertvector(q0 * SC, bf16x8);
    const bf16x8 a_hi = __builtin_convertvector(q1 * SC, bf16x8);

    if (t < 3) red[t] = 0.0f;

    typedef __bf16 (*buf_t)[72];
    buf_t rd = (buf_t)&Ks[0][0][0];
    buf_t wr = (buf_t)&Ks[1][0][0];
    buf_t ex = (buf_t)&Ks[2][0][0];

    WRITE(rd);                                  // chunk 0 -> buf0 (waits its vmcnt)
    ISSUE(1);                                   // chunk 1 -> regs
    __syncthreads();                            // full drain once: buf0 + red ready

    float m[4], Zs[4], Z2[4], sm[4];
#pragma unroll
    for (int i = 0; i < 4; ++i) { m[i] = -INFINITY; Zs[i] = 0.f; Z2[i] = 0.f; sm[i] = 0.f; }

    // ---- main loop: ONE barrier per chunk, loads in flight across it ----
    for (int c = 0; c < NKT; ++c) {
        WRITE(wr);                              // chunk c+1 (vmcnt wait = consume point)
        ISSUE(c + 2);                           // chunk c+2, stays in flight
        asm volatile("s_waitcnt lgkmcnt(0)" ::: "memory");
        __builtin_amdgcn_s_barrier();
        asm volatile("" ::: "memory");
        COMPUTE(rd);                            // chunk c
        buf_t tmp = rd; rd = wr; wr = ex; ex = tmp;
    }

    // ---- reduce across the 16 column-lanes sharing each q-row ----
#pragma unroll
    for (int off = 1; off < 16; off <<= 1) {
#pragma unroll
        for (int i = 0; i < 4; ++i) {
            m[i]   = fmaxf(m[i], __shfl_xor(m[i], off, 64));
            Zs[i] += __shfl_xor(Zs[i], off, 64);
            Z2[i] += __shfl_xor(Z2[i], off, 64);
            sm[i] += __shfl_xor(sm[i], off, 64);
        }
    }
    if (lrow == 0) {
        const float LN2 = 0.69314718055994530942f;
        float psum = 0.f, pmax = 0.f, pvar = 0.f;
#pragma unroll
        for (int i = 0; i < 4; ++i) {
            psum += sm[i];
            pmax += m[i];
            const float iz = 1.0f / Zs[i];
            // var(probs, ddof=1) = (Z2/Z^2 - 1/n)/(n-1); scale-invariant
            pvar += (Z2[i] * iz * iz - (1.0f / 2048.0f)) * (1.0f / 2047.0f);
        }
        atomicAdd(&red[0], psum * LN2);         // back to natural-log domain
        atomicAdd(&red[1], pmax * LN2);
        atomicAdd(&red[2], pvar);
    }
    __syncthreads();
    if (t == 0) {
        atomicAdd(&ws[bh * 3 + 0], red[0]);
        atomicAdd(&ws[bh * 3 + 1], red[1]);
        atomicAdd(&ws[bh * 3 + 2], red[2]);
        __threadfence();
        const int old = atomicAdd((int*)(ws + 96), 1);
        lastF = (old == NBLK - 1);
    }
    __syncthreads();
    if (!lastF) return;

    // =========================== MLP head (last block) ======================
    float* H1    = (float*)&Ks[0][0][0];   // 32*65 floats
    float* featL = H1 + 32 * 65;           // 96 floats
    float* logtL = featL + 96;             // 32 floats   (8832 B < 27 KB)

    if (t < 96)               featL[t] = atomicAdd(&ws[t], 0.0f); // coherent read
    if (t >= 96 && t < 128)   logtL[t - 96] = 0.0f;
    __syncthreads();

    if (t < 64) {
        const float w1a = W1[t], w1b = W1[64 + t], w1c = W1[128 + t], bb1 = b1[t];
        for (int b = 0; b < 32; ++b) {
            const float f0 = featL[b * 3 + 0] * (1.0f / ((float)S * (float)S));
            const float f1 = featL[b * 3 + 1] * (1.0f / (float)S);
            const float f2 = featL[b * 3 + 2] * (1.0f / (float)S);
            H1[b * 65 + t] = gelu_exact(f0 * w1a + f1 * w1b + f2 * w1c + bb1);
        }
    }
    __syncthreads();
    {
        // 256 threads: 8 threads per bh, 8 hidden-2 units each
        const int b = t >> 3, jb = (t & 7) * 8;
        float acc[8];
#pragma unroll
        for (int u = 0; u < 8; ++u) acc[u] = 0.0f;
        for (int k = 0; k < 64; ++k) {
            const float hk = H1[b * 65 + k];
            const float4 wa = *(const float4*)&W2[k * 64 + jb];
            const float4 wb = *(const float4*)&W2[k * 64 + jb + 4];
            acc[0] += hk * wa.x; acc[1] += hk * wa.y;
            acc[2] += hk * wa.z; acc[3] += hk * wa.w;
            acc[4] += hk * wb.x; acc[5] += hk * wb.y;
            acc[6] += hk * wb.z; acc[7] += hk * wb.w;
        }
        float part = 0.0f;
#pragma unroll
        for (int u = 0; u < 8; ++u)
            part += gelu_exact(acc[u] + b2[jb + u]) * W3[jb + u];
        atomicAdd(&logtL[b], part);
    }
    __syncthreads();
    if (t < 32) {
        float lt = logtL[t] + b3[0];
        lt = fminf(fmaxf(lt, -2.3025850929940457f), 2.3025850929940457f);
        out[t] = expf(lt);
    }
}

// ---------------------------------------------------------------------------
extern "C" void kernel_launch(void* const* d_in, const int* in_sizes, int n_in,
                              void* d_out, int out_size, void* d_ws, size_t ws_size,
                              hipStream_t stream)
{
    const float* Q  = (const float*)d_in[0];
    const float* K  = (const float*)d_in[1];
    const float* W1 = (const float*)d_in[2];
    const float* b1 = (const float*)d_in[3];
    const float* W2 = (const float*)d_in[4];
    const float* b2 = (const float*)d_in[5];
    const float* W3 = (const float*)d_in[6];
    const float* b3 = (const float*)d_in[7];
    float* out = (float*)d_out;
    float* ws  = (float*)d_ws;

    // zero the 96 stat accumulators + the int block counter at ws[96]
    hipMemsetAsync(ws, 0, 512, stream);

    dim3 grid(NBH, NQT);   // bh fastest -> each bh's K pinned to one XCD L2
    fused_attn_stats_mlp<<<grid, NTHR, 0, stream>>>(Q, K, W1, b1, W2, b2, W3, b3, ws, out);
}